// Round 4
// baseline (129.616 us; speedup 1.0000x reference)
//
#include <hip/hip_runtime.h>
#include <stdint.h>

typedef __attribute__((ext_vector_type(8))) short bf16x8;
typedef __attribute__((ext_vector_type(4))) short bf16x4;
typedef __attribute__((ext_vector_type(4))) float f32x4;
typedef unsigned short u16t;

#define DEVINL static __device__ __forceinline__

DEVINL u16t f2bf(float f) {
  union { float f; unsigned u; } v; v.f = f;
  return (u16t)((v.u + 0x7FFFu + ((v.u >> 16) & 1u)) >> 16);  // RNE, inputs finite
}

DEVINL float exp2_fast(float x) {
  float r; asm("v_exp_f32 %0, %1" : "=v"(r) : "v"(x)); return r;
}
DEVINL unsigned cvt_pk_bf16(float a, float b) {  // lo16=bf16(a), hi16=bf16(b)
  unsigned r; asm("v_cvt_pk_bf16_f32 %0, %1, %2" : "=v"(r) : "v"(a), "v"(b)); return r;
}
DEVINL float max3f(float a, float b, float c) {
  float r; asm("v_max3_f32 %0, %1, %2, %3" : "=v"(r) : "v"(a), "v"(b), "v"(c)); return r;
}

DEVINL void gload16(const void* g, void* l) {
  __builtin_amdgcn_global_load_lds((const __attribute__((address_space(1))) void*)g,
                                   (__attribute__((address_space(3))) void*)l, 16, 0, 0);
}

// ---------------- fp32 -> bf16 convert (all 5 tensors, one launch) ----------------
__global__ __launch_bounds__(256)
void cvt5_kernel(const float* __restrict__ x, const float* __restrict__ wq,
                 const float* __restrict__ wk, const float* __restrict__ wv,
                 const float* __restrict__ wo, u16t* __restrict__ x_bf,
                 u16t* __restrict__ wqkv, u16t* __restrict__ wo_bf) {
  const int bid = blockIdx.x;
  const float* src; u16t* dst; int off;
  if (bid < 2048) { src = x; dst = x_bf; off = bid * 2048; }
  else {
    const int j = bid - 2048, sel = j >> 9;
    off = (j & 511) * 2048;
    if (sel == 0)      { src = wq; dst = wqkv; }
    else if (sel == 1) { src = wk; dst = wqkv + 1048576; }
    else if (sel == 2) { src = wv; dst = wqkv + 2097152; }
    else               { src = wo; dst = wo_bf; }
  }
  const int i = off + threadIdx.x * 8;
  float4 a = *(const float4*)(src + i);
  float4 b = *(const float4*)(src + i + 4);
  union { bf16x8 v; u16t u[8]; } o;
  o.u[0] = f2bf(a.x); o.u[1] = f2bf(a.y); o.u[2] = f2bf(a.z); o.u[3] = f2bf(a.w);
  o.u[4] = f2bf(b.x); o.u[5] = f2bf(b.y); o.u[6] = f2bf(b.z); o.u[7] = f2bf(b.w);
  *(bf16x8*)(dst + i) = o.v;
}

// ---------------- bf16 GEMM: C[M,N] = A[M,K] * Bw[N,K]^T + bias ----------------
// M=4096, K=1024. MODE 0: N=3072 (Wq|Wk|Wv): Q scaled by 0.125*log2(e), V written
// transposed as Vt[b][h][d][s]. MODE 1: N=1024 (Wo), fp32 out.
template <int MODE>
__global__ __launch_bounds__(256, 2)
void gemm_kernel(const u16t* __restrict__ A, const u16t* __restrict__ Bw,
                 const float* __restrict__ bias0, const float* __restrict__ bias1,
                 const float* __restrict__ bias2, void* __restrict__ outp) {
  __shared__ __attribute__((aligned(16))) u16t As[128 * 64];
  __shared__ __attribute__((aligned(16))) u16t Bs[128 * 64];
  const int tid = threadIdx.x;
  const int w = tid >> 6, l = tid & 63;
  const int wm = w >> 1, wn = w & 1;
  const int bm = blockIdx.x, bn = blockIdx.y;
  const int g = l >> 4, r16 = l & 15;
  const int srow = l >> 3, sslot = l & 7;

  f32x4 acc[4][4];
#pragma unroll
  for (int m = 0; m < 4; ++m)
#pragma unroll
    for (int n = 0; n < 4; ++n) acc[m][n] = f32x4{0.f, 0.f, 0.f, 0.f};

  const size_t arow0 = (size_t)bm * 128;
  const size_t brow0 = (size_t)bn * 128;

  for (int kt = 0; kt < 16; ++kt) {
    __syncthreads();
#pragma unroll
    for (int i = 0; i < 4; ++i) {
      const int row = (i * 4 + w) * 8 + srow;
      const int colA = kt * 64 + ((sslot ^ (row & 7)) * 8);
      gload16(A + (arow0 + row) * 1024 + colA, (char*)As + (i * 4 + w) * 1024);
      gload16(Bw + (brow0 + row) * 1024 + colA, (char*)Bs + (i * 4 + w) * 1024);
    }
    asm volatile("s_waitcnt vmcnt(0)" ::: "memory");
    __syncthreads();
#pragma unroll
    for (int kk = 0; kk < 2; ++kk) {
      bf16x8 af[4], bfr[4];
#pragma unroll
      for (int m = 0; m < 4; ++m) {
        const int rr = wm * 64 + m * 16 + r16;
        af[m] = *(const bf16x8*)((const char*)As + rr * 128 + (((kk * 4 + g) ^ (rr & 7)) * 16));
      }
#pragma unroll
      for (int n = 0; n < 4; ++n) {
        const int rr = wn * 64 + n * 16 + r16;
        bfr[n] = *(const bf16x8*)((const char*)Bs + rr * 128 + (((kk * 4 + g) ^ (rr & 7)) * 16));
      }
#pragma unroll
      for (int m = 0; m < 4; ++m)
#pragma unroll
        for (int n = 0; n < 4; ++n)
          acc[m][n] = __builtin_amdgcn_mfma_f32_16x16x32_bf16(af[m], bfr[n], acc[m][n], 0, 0, 0);
    }
  }

  if (MODE == 0) {
    const int mat = bn >> 3;  // 0=Q,1=K,2=V
    if (mat == 2) {
      u16t* vt = (u16t*)outp + 8388608u;
#pragma unroll
      for (int n = 0; n < 4; ++n) {
        const int col = ((bn & 7) * 128) + wn * 64 + n * 16 + r16;  // h*64+d
        const int hh = col >> 6, dd = col & 63;
        const float bv = bias2[col];
#pragma unroll
        for (int m = 0; m < 4; ++m) {
          const int row0 = bm * 128 + wm * 64 + m * 16 + g * 4;
          const int b_ = row0 >> 11, s_ = row0 & 2047;
          union { bf16x4 v; u16t u[4]; } o4;
#pragma unroll
          for (int i = 0; i < 4; ++i) o4.u[i] = f2bf(acc[m][n][i] + bv);
          *(bf16x4*)(vt + ((size_t)(b_ * 16 + hh) * 64 + dd) * 2048 + s_) = o4.v;
        }
      }
    } else {
      const float* bias = (mat == 0) ? bias0 : bias1;
      // Q: fold 1/sqrt(64) * log2(e) so attention works in exp2 domain
      const float scale = (mat == 0) ? 0.18033688f : 1.0f;
      u16t* o = (u16t*)outp + (size_t)mat * 4194304u;
#pragma unroll
      for (int n = 0; n < 4; ++n) {
        const int col = ((bn & 7) * 128) + wn * 64 + n * 16 + r16;
        const float bv = bias[col];
#pragma unroll
        for (int m = 0; m < 4; ++m) {
          const int row = bm * 128 + wm * 64 + m * 16 + g * 4;
#pragma unroll
          for (int i = 0; i < 4; ++i)
            o[(size_t)(row + i) * 1024 + col] = f2bf((acc[m][n][i] + bv) * scale);
        }
      }
    }
  } else {
    float* o = (float*)outp;
#pragma unroll
    for (int n = 0; n < 4; ++n) {
      const int col = bn * 128 + wn * 64 + n * 16 + r16;
      const float bv = bias0[col];
#pragma unroll
      for (int m = 0; m < 4; ++m) {
        const int row = bm * 128 + wm * 64 + m * 16 + g * 4;
#pragma unroll
        for (int i = 0; i < 4; ++i)
          o[(size_t)(row + i) * 1024 + col] = acc[m][n][i] + bv;
      }
    }
  }
}

// ---------------- flash attention with ALiBi (bidirectional) ----------------
// exp2 domain, reverse tile order, bias folded into MFMA C-init (see R2 notes).
// NEW: 3-buffer LDS ring + ONE raw s_barrier per iter + counted vmcnt(4) —
// loads for tile t+2 issued right after barrier(t), awaited 2 iters later.
// vmcnt(0) drain only on the last iteration. Row-sum via ones-MFMA.
__global__ __launch_bounds__(256, 2)
void attn_kernel(const u16t* __restrict__ Qb, const u16t* __restrict__ Kb,
                 const u16t* __restrict__ Vtb, const float* __restrict__ slopes,
                 u16t* __restrict__ Ctx) {
  __shared__ __attribute__((aligned(16))) u16t Kl[3][4096];  // [64 keys][64 d] swz
  __shared__ __attribute__((aligned(16))) u16t Vl[3][4096];  // [64 d][64 keys] swz
  const int tid = threadIdx.x;
  const int w = tid >> 6, l = tid & 63;
  const int g = l >> 4, r = l & 15;
  const int qt = blockIdx.x, bh = blockIdx.y;
  const int b = bh >> 4, h = bh & 15;
  const float slope2 = slopes[h] * 1.44269504f;
  const int qpos = qt * 64 + w * 16 + r;
  const size_t base = (size_t)b * 2097152 + (size_t)h * 64;

  const u16t* qrow = Qb + base + (size_t)qpos * 1024;
  const bf16x8 qf0 = *(const bf16x8*)(qrow + g * 8);
  const bf16x8 qf1 = *(const bf16x8*)(qrow + 32 + g * 8);
  asm volatile("s_waitcnt vmcnt(0)" ::: "memory");  // Q in regs; vmcnt clean

  // K A-frag offsets: row perm sigma(r)=8*(r>>2)+(r&3) (+{0,4,32,36});
  // K-tile swizzle mask (row&3)^((row>>1)&4) -> every 8-lane phase is a slot perm.
  const int sig = 8 * (r >> 2) + (r & 3);
  const int toffs[4] = {0, 4, 32, 36};
  int koff[4][2], voff[4][2];
#pragma unroll
  for (int t = 0; t < 4; ++t) {
    const int row = toffs[t] + sig;
    const int mk = (row & 3) ^ ((row >> 1) & 4);
#pragma unroll
    for (int hh = 0; hh < 2; ++hh) koff[t][hh] = row * 128 + (((hh * 4 + g) ^ mk) * 16);
  }
#pragma unroll
  for (int db = 0; db < 4; ++db) {
    const int row = 16 * db + r;  // V-tile: classic (row&7) swizzle
#pragma unroll
    for (int hh = 0; hh < 2; ++hh) voff[db][hh] = row * 128 + (((hh * 4 + g) ^ (row & 7)) * 16);
  }

  // staging source geometry (pass p=0,1; LDS dest linear, source pre-swizzled)
  int k_row[2], k_u[2], v_u[2];
#pragma unroll
  for (int p = 0; p < 2; ++p) {
    const int line = p * 32 + w * 8 + (l >> 3);
    k_row[p] = line;
    k_u[p] = ((l & 7) ^ ((line & 3) ^ ((line >> 1) & 4))) * 8;
    v_u[p] = ((l & 7) ^ (line & 7)) * 8;
  }

  // ALiBi C-init frags: cv[t][i] = slope2 * local_j for st[t][i] <-> key toff+8g+i
  f32x4 cv[4];
#pragma unroll
  for (int t = 0; t < 4; ++t)
#pragma unroll
    for (int i = 0; i < 4; ++i) cv[t][i] = slope2 * (float)(toffs[t] + 8 * g + i);

  const float d64 = slope2 * 64.f;
  float mj = -3.0e38f;
  f32x4 oc[4], sacc;
#pragma unroll
  for (int d = 0; d < 4; ++d) oc[d] = f32x4{0.f, 0.f, 0.f, 0.f};
  sacc = f32x4{0.f, 0.f, 0.f, 0.f};
  union { bf16x8 v; u16t u[8]; } ones;
#pragma unroll
  for (int i = 0; i < 8; ++i) ones.u[i] = 0x3F80;  // 1.0 bf16

  const u16t* Krow = Kb + base;
  const u16t* Vrow = Vtb + (size_t)(b * 16 + h) * 131072;  // [64][2048]

#define STAGE(kt_, b_)                                                              \
  {                                                                                 \
    _Pragma("unroll") for (int p = 0; p < 2; ++p) {                                 \
      gload16(Krow + (size_t)((kt_) * 64 + k_row[p]) * 1024 + k_u[p],               \
              (char*)Kl + (b_) * 8192 + p * 4096 + w * 1024);                       \
      gload16(Vrow + (size_t)k_row[p] * 2048 + (kt_) * 64 + v_u[p],                 \
              (char*)Vl + (b_) * 8192 + p * 4096 + w * 1024);                       \
    }                                                                               \
  }

  // prologue: tiles 31 -> buf0, 30 -> buf1 (8 loads outstanding)
  STAGE(31, 0)
  STAGE(30, 1)

  for (int it = 0; it < 32; ++it) {
    const int kt = 31 - it;
    const int buf = it % 3;
    // own tile-t loads are the oldest 4 of 8 outstanding
    if (it == 31) { asm volatile("s_waitcnt vmcnt(0)" ::: "memory"); }
    else          { asm volatile("s_waitcnt vmcnt(4)" ::: "memory"); }
    __builtin_amdgcn_s_barrier();       // all waves: tile t staged, compute t-1 done
    asm volatile("" ::: "memory");      // fence IR motion across the barrier
    __builtin_amdgcn_sched_barrier(0);
    if (it + 2 < 32) STAGE(kt - 2, (it + 2) % 3)  // into buffer freed by barrier
    if (it) mj += d64;                  // local-bias coordinate shift

    const char* KB = (const char*)Kl + buf * 8192;
    const char* VB = (const char*)Vl + buf * 8192;

    f32x4 st[4];
#pragma unroll
    for (int t = 0; t < 4; ++t) {
      st[t] = __builtin_amdgcn_mfma_f32_16x16x32_bf16(
          *(const bf16x8*)(KB + koff[t][0]), qf0, cv[t], 0, 0, 0);
      st[t] = __builtin_amdgcn_mfma_f32_16x16x32_bf16(
          *(const bf16x8*)(KB + koff[t][1]), qf1, st[t], 0, 0, 0);
    }

    const float g1 = max3f(st[0][0], st[0][1], st[0][2]);
    const float g2 = max3f(st[0][3], st[1][0], st[1][1]);
    const float g3 = max3f(st[1][2], st[1][3], st[2][0]);
    const float g4 = max3f(st[2][1], st[2][2], st[2][3]);
    const float g5 = max3f(st[3][0], st[3][1], st[3][2]);
    const float tm = fmaxf(max3f(g1, g2, g3), max3f(g4, g5, st[3][3]));
    if (__any(tm > mj)) {  // rare: reverse order => max found in first tiles
      float tr = fmaxf(tm, __shfl_xor(tm, 16));
      tr = fmaxf(tr, __shfl_xor(tr, 32));
      const float mn = fmaxf(mj, tr);
      const float corr = exp2_fast(mj - mn);
#pragma unroll
      for (int d = 0; d < 4; ++d) {
        oc[d][0] *= corr; oc[d][1] *= corr; oc[d][2] *= corr; oc[d][3] *= corr;
      }
      sacc[0] *= corr; sacc[1] *= corr; sacc[2] *= corr; sacc[3] *= corr;
      mj = mn;
    }

    float pe[16];
#pragma unroll
    for (int t = 0; t < 4; ++t)
#pragma unroll
      for (int i = 0; i < 4; ++i) pe[t * 4 + i] = exp2_fast(st[t][i] - mj);
    union { bf16x8 v; unsigned q[4]; } pb0, pb1;
#pragma unroll
    for (int j = 0; j < 4; ++j) {
      pb0.q[j] = cvt_pk_bf16(pe[j * 2], pe[j * 2 + 1]);
      pb1.q[j] = cvt_pk_bf16(pe[8 + j * 2], pe[8 + j * 2 + 1]);
    }

#pragma unroll
    for (int db = 0; db < 4; ++db) {
      oc[db] = __builtin_amdgcn_mfma_f32_16x16x32_bf16(
          *(const bf16x8*)(VB + voff[db][0]), pb0.v, oc[db], 0, 0, 0);
      oc[db] = __builtin_amdgcn_mfma_f32_16x16x32_bf16(
          *(const bf16x8*)(VB + voff[db][1]), pb1.v, oc[db], 0, 0, 0);
    }
    sacc = __builtin_amdgcn_mfma_f32_16x16x32_bf16(ones.v, pb0.v, sacc, 0, 0, 0);
    sacc = __builtin_amdgcn_mfma_f32_16x16x32_bf16(ones.v, pb1.v, sacc, 0, 0, 0);
  }
#undef STAGE

  const float inv = 1.0f / sacc[0];
  u16t* orow = Ctx + base + (size_t)qpos * 1024;
#pragma unroll
  for (int d = 0; d < 4; ++d) {
    union { bf16x4 v; u16t u[4]; } o4;
#pragma unroll
    for (int i = 0; i < 4; ++i) o4.u[i] = f2bf(oc[d][i] * inv);
    *(bf16x4*)(orow + d * 16 + g * 4) = o4.v;
  }
}

extern "C" void kernel_launch(void* const* d_in, const int* in_sizes, int n_in,
                              void* d_out, int out_size, void* d_ws, size_t ws_size,
                              hipStream_t stream) {
  const float* x = (const float*)d_in[0];
  const float* Wq = (const float*)d_in[1];
  const float* bq = (const float*)d_in[2];
  const float* Wk = (const float*)d_in[3];
  const float* bk = (const float*)d_in[4];
  const float* Wv = (const float*)d_in[5];
  const float* bv = (const float*)d_in[6];
  const float* Wo = (const float*)d_in[7];
  const float* bo = (const float*)d_in[8];
  const float* slopes = (const float*)d_in[9];
  if (ws_size < (size_t)(48u << 20)) return;
  char* ws = (char*)d_ws;
  u16t* x_bf = (u16t*)(ws);                  //  8 MB: x bf16 [4096][1024]
  u16t* wqkv = (u16t*)(ws + (8u << 20));     //  6 MB: Wq|Wk|Wv bf16
  u16t* wo_bf = (u16t*)(ws + (14u << 20));   //  2 MB: Wo bf16
  u16t* q_bf = (u16t*)(ws + (16u << 20));    // 24 MB: Q | K | Vt bf16
  u16t* ctx_bf = (u16t*)(ws + (40u << 20));  //  8 MB: ctx bf16

  cvt5_kernel<<<4096, 256, 0, stream>>>(x, Wq, Wk, Wv, Wo, x_bf, wqkv, wo_bf);
  gemm_kernel<0><<<dim3(32, 24), 256, 0, stream>>>(x_bf, wqkv, bq, bk, bv, (void*)q_bf);
  attn_kernel<<<dim3(32, 32), 256, 0, stream>>>(q_bf, q_bf + 4194304, q_bf + 8388608,
                                                slopes, ctx_bf);
  gemm_kernel<1><<<dim3(32, 8), 256, 0, stream>>>(ctx_bf, wo_bf, bo, bo, bo, d_out);
}

// Round 5
// 127.202 us; speedup vs baseline: 1.0190x; 1.0190x over previous
//
#include <hip/hip_runtime.h>
#include <stdint.h>

typedef __attribute__((ext_vector_type(8))) short bf16x8;
typedef __attribute__((ext_vector_type(4))) short bf16x4;
typedef __attribute__((ext_vector_type(4))) float f32x4;
typedef unsigned short u16t;

#define DEVINL static __device__ __forceinline__

DEVINL u16t f2bf(float f) {
  union { float f; unsigned u; } v; v.f = f;
  return (u16t)((v.u + 0x7FFFu + ((v.u >> 16) & 1u)) >> 16);  // RNE, inputs finite
}

DEVINL float exp2_fast(float x) {
  float r; asm("v_exp_f32 %0, %1" : "=v"(r) : "v"(x)); return r;
}
DEVINL unsigned cvt_pk_bf16(float a, float b) {  // lo16=bf16(a), hi16=bf16(b)
  unsigned r; asm("v_cvt_pk_bf16_f32 %0, %1, %2" : "=v"(r) : "v"(a), "v"(b)); return r;
}
DEVINL float max3f(float a, float b, float c) {
  float r; asm("v_max3_f32 %0, %1, %2, %3" : "=v"(r) : "v"(a), "v"(b), "v"(c)); return r;
}

DEVINL void gload16(const void* g, void* l) {
  __builtin_amdgcn_global_load_lds((const __attribute__((address_space(1))) void*)g,
                                   (__attribute__((address_space(3))) void*)l, 16, 0, 0);
}

// ---------------- fp32 -> bf16 convert (all 5 tensors, one launch) ----------------
__global__ __launch_bounds__(256)
void cvt5_kernel(const float* __restrict__ x, const float* __restrict__ wq,
                 const float* __restrict__ wk, const float* __restrict__ wv,
                 const float* __restrict__ wo, u16t* __restrict__ x_bf,
                 u16t* __restrict__ wqkv, u16t* __restrict__ wo_bf) {
  const int bid = blockIdx.x;
  const float* src; u16t* dst; int off;
  if (bid < 2048) { src = x; dst = x_bf; off = bid * 2048; }
  else {
    const int j = bid - 2048, sel = j >> 9;
    off = (j & 511) * 2048;
    if (sel == 0)      { src = wq; dst = wqkv; }
    else if (sel == 1) { src = wk; dst = wqkv + 1048576; }
    else if (sel == 2) { src = wv; dst = wqkv + 2097152; }
    else               { src = wo; dst = wo_bf; }
  }
  const int i = off + threadIdx.x * 8;
  float4 a = *(const float4*)(src + i);
  float4 b = *(const float4*)(src + i + 4);
  union { bf16x8 v; u16t u[8]; } o;
  o.u[0] = f2bf(a.x); o.u[1] = f2bf(a.y); o.u[2] = f2bf(a.z); o.u[3] = f2bf(a.w);
  o.u[4] = f2bf(b.x); o.u[5] = f2bf(b.y); o.u[6] = f2bf(b.z); o.u[7] = f2bf(b.w);
  *(bf16x8*)(dst + i) = o.v;
}

// ---------------- bf16 GEMM: C[M,N] = A[M,K] * Bw[N,K]^T + bias ----------------
// M=4096, K=1024. MODE 0: N=3072 (Wq|Wk|Wv): Q scaled by 0.125*log2(e), V written
// transposed as Vt[b][h][d][s]. MODE 1: N=1024 (Wo), fp32 out.
template <int MODE>
__global__ __launch_bounds__(256, 2)
void gemm_kernel(const u16t* __restrict__ A, const u16t* __restrict__ Bw,
                 const float* __restrict__ bias0, const float* __restrict__ bias1,
                 const float* __restrict__ bias2, void* __restrict__ outp) {
  __shared__ __attribute__((aligned(16))) u16t As[128 * 64];
  __shared__ __attribute__((aligned(16))) u16t Bs[128 * 64];
  const int tid = threadIdx.x;
  const int w = tid >> 6, l = tid & 63;
  const int wm = w >> 1, wn = w & 1;
  const int bm = blockIdx.x, bn = blockIdx.y;
  const int g = l >> 4, r16 = l & 15;
  const int srow = l >> 3, sslot = l & 7;

  f32x4 acc[4][4];
#pragma unroll
  for (int m = 0; m < 4; ++m)
#pragma unroll
    for (int n = 0; n < 4; ++n) acc[m][n] = f32x4{0.f, 0.f, 0.f, 0.f};

  const size_t arow0 = (size_t)bm * 128;
  const size_t brow0 = (size_t)bn * 128;

  for (int kt = 0; kt < 16; ++kt) {
    __syncthreads();
#pragma unroll
    for (int i = 0; i < 4; ++i) {
      const int row = (i * 4 + w) * 8 + srow;
      const int colA = kt * 64 + ((sslot ^ (row & 7)) * 8);
      gload16(A + (arow0 + row) * 1024 + colA, (char*)As + (i * 4 + w) * 1024);
      gload16(Bw + (brow0 + row) * 1024 + colA, (char*)Bs + (i * 4 + w) * 1024);
    }
    asm volatile("s_waitcnt vmcnt(0)" ::: "memory");
    __syncthreads();
#pragma unroll
    for (int kk = 0; kk < 2; ++kk) {
      bf16x8 af[4], bfr[4];
#pragma unroll
      for (int m = 0; m < 4; ++m) {
        const int rr = wm * 64 + m * 16 + r16;
        af[m] = *(const bf16x8*)((const char*)As + rr * 128 + (((kk * 4 + g) ^ (rr & 7)) * 16));
      }
#pragma unroll
      for (int n = 0; n < 4; ++n) {
        const int rr = wn * 64 + n * 16 + r16;
        bfr[n] = *(const bf16x8*)((const char*)Bs + rr * 128 + (((kk * 4 + g) ^ (rr & 7)) * 16));
      }
#pragma unroll
      for (int m = 0; m < 4; ++m)
#pragma unroll
        for (int n = 0; n < 4; ++n)
          acc[m][n] = __builtin_amdgcn_mfma_f32_16x16x32_bf16(af[m], bfr[n], acc[m][n], 0, 0, 0);
    }
  }

  if (MODE == 0) {
    const int mat = bn >> 3;  // 0=Q,1=K,2=V
    if (mat == 2) {
      u16t* vt = (u16t*)outp + 8388608u;
#pragma unroll
      for (int n = 0; n < 4; ++n) {
        const int col = ((bn & 7) * 128) + wn * 64 + n * 16 + r16;  // h*64+d
        const int hh = col >> 6, dd = col & 63;
        const float bv = bias2[col];
#pragma unroll
        for (int m = 0; m < 4; ++m) {
          const int row0 = bm * 128 + wm * 64 + m * 16 + g * 4;
          const int b_ = row0 >> 11, s_ = row0 & 2047;
          union { bf16x4 v; u16t u[4]; } o4;
#pragma unroll
          for (int i = 0; i < 4; ++i) o4.u[i] = f2bf(acc[m][n][i] + bv);
          *(bf16x4*)(vt + ((size_t)(b_ * 16 + hh) * 64 + dd) * 2048 + s_) = o4.v;
        }
      }
    } else {
      const float* bias = (mat == 0) ? bias0 : bias1;
      // Q: fold 1/sqrt(64) * log2(e) so attention works in exp2 domain
      const float scale = (mat == 0) ? 0.18033688f : 1.0f;
      u16t* o = (u16t*)outp + (size_t)mat * 4194304u;
#pragma unroll
      for (int n = 0; n < 4; ++n) {
        const int col = ((bn & 7) * 128) + wn * 64 + n * 16 + r16;
        const float bv = bias[col];
#pragma unroll
        for (int m = 0; m < 4; ++m) {
          const int row = bm * 128 + wm * 64 + m * 16 + g * 4;
#pragma unroll
          for (int i = 0; i < 4; ++i)
            o[(size_t)(row + i) * 1024 + col] = f2bf((acc[m][n][i] + bv) * scale);
        }
      }
    }
  } else {
    float* o = (float*)outp;
#pragma unroll
    for (int n = 0; n < 4; ++n) {
      const int col = bn * 128 + wn * 64 + n * 16 + r16;
      const float bv = bias0[col];
#pragma unroll
      for (int m = 0; m < 4; ++m) {
        const int row = bm * 128 + wm * 64 + m * 16 + g * 4;
#pragma unroll
        for (int i = 0; i < 4; ++i)
          o[(size_t)(row + i) * 1024 + col] = acc[m][n][i] + bv;
      }
    }
  }
}

// ---------------- flash attention with ALiBi (bidirectional) ----------------
// exp2 domain, reverse tile order, bias folded into MFMA C-init. 3-buffer LDS
// ring + one raw s_barrier/iter + counted vmcnt(2) (drain only at last iter).
// KVBLK=32 -> 24KB LDS/block so 4+ blocks stay resident (occupancy carries the
// latency chain). K tile [32][64] mask (row&3)^((row>>1)&4); V tile [64 d][32
// keys] (64B rows) mask (row&3)^((row>>2)&3) — both phase-conflict-free.
__global__ __launch_bounds__(256, 2)
void attn_kernel(const u16t* __restrict__ Qb, const u16t* __restrict__ Kb,
                 const u16t* __restrict__ Vtb, const float* __restrict__ slopes,
                 u16t* __restrict__ Ctx) {
  __shared__ __attribute__((aligned(16))) u16t Kl[3][2048];  // 3 x [32 keys][64 d]
  __shared__ __attribute__((aligned(16))) u16t Vl[3][2048];  // 3 x [64 d][32 keys]
  const int tid = threadIdx.x;
  const int w = tid >> 6, l = tid & 63;
  const int g = l >> 4, r = l & 15;
  const int qt = blockIdx.x, bh = blockIdx.y;
  const int b = bh >> 4, h = bh & 15;
  const float slope2 = slopes[h] * 1.44269504f;
  const int qpos = qt * 64 + w * 16 + r;
  const size_t base = (size_t)b * 2097152 + (size_t)h * 64;

  const u16t* qrow = Qb + base + (size_t)qpos * 1024;
  const bf16x8 qf0 = *(const bf16x8*)(qrow + g * 8);
  const bf16x8 qf1 = *(const bf16x8*)(qrow + 32 + g * 8);
  asm volatile("s_waitcnt vmcnt(0)" ::: "memory");  // Q in regs; vmcnt clean

  // K A-frag offsets: row perm sigma(r)=8*(r>>2)+(r&3), tiles toff {0,4}.
  const int sig = 8 * (r >> 2) + (r & 3);
  const int toffs[2] = {0, 4};
  int koff[2][2], voff[4];
#pragma unroll
  for (int t = 0; t < 2; ++t) {
    const int row = toffs[t] + sig;
    const int mk = (row & 3) ^ ((row >> 1) & 4);
#pragma unroll
    for (int hh = 0; hh < 2; ++hh) koff[t][hh] = row * 128 + (((hh * 4 + g) ^ mk) * 16);
  }
#pragma unroll
  for (int db = 0; db < 4; ++db) {
    const int row = 16 * db + r;  // V tile 64B rows, 4 slots
    const int vm = (row & 3) ^ ((row >> 2) & 3);
    voff[db] = row * 64 + ((g ^ vm) * 16);
  }

  // staging source geometry (LDS dest linear, source pre-swizzled)
  const int krow_s = w * 8 + (l >> 3);              // 0..31
  const int ku_s = (((l & 7) ^ ((krow_s & 3) ^ ((krow_s >> 1) & 4)))) * 8;
  const int vrow_s = w * 16 + (l >> 2);             // 0..63
  const int vu_s = (((l & 3) ^ ((vrow_s & 3) ^ ((vrow_s >> 2) & 3)))) * 8;

  // ALiBi C-init: cv[t][i] = slope2 * local_j for st[t][i] <-> key toff[t]+8g+i
  f32x4 cv[2];
#pragma unroll
  for (int t = 0; t < 2; ++t)
#pragma unroll
    for (int i = 0; i < 4; ++i) cv[t][i] = slope2 * (float)(toffs[t] + 8 * g + i);

  const float d32 = slope2 * 32.f;
  float mj = -3.0e38f;
  f32x4 oc[4], sacc;
#pragma unroll
  for (int d = 0; d < 4; ++d) oc[d] = f32x4{0.f, 0.f, 0.f, 0.f};
  sacc = f32x4{0.f, 0.f, 0.f, 0.f};
  union { bf16x8 v; u16t u[8]; } ones;
#pragma unroll
  for (int i = 0; i < 8; ++i) ones.u[i] = 0x3F80;  // 1.0 bf16

  const u16t* Krow = Kb + base;
  const u16t* Vrow = Vtb + (size_t)(b * 16 + h) * 131072;  // [64][2048]

#define STAGE(kt_, b_)                                                            \
  {                                                                               \
    gload16(Krow + (size_t)((kt_) * 32 + krow_s) * 1024 + ku_s,                   \
            (char*)Kl + (b_) * 4096 + w * 1024);                                  \
    gload16(Vrow + (size_t)vrow_s * 2048 + (kt_) * 32 + vu_s,                     \
            (char*)Vl + (b_) * 4096 + w * 1024);                                  \
  }

  // prologue: tiles 63 -> buf0, 62 -> buf1 (4 loads outstanding)
  STAGE(63, 0)
  STAGE(62, 1)

  for (int it = 0; it < 64; ++it) {
    const int kt = 63 - it;
    const int buf = it % 3;
    // own tile-t loads are the oldest 2 outstanding
    if (it == 63) { asm volatile("s_waitcnt vmcnt(0)" ::: "memory"); }
    else          { asm volatile("s_waitcnt vmcnt(2)" ::: "memory"); }
    __builtin_amdgcn_s_barrier();   // all waves: tile staged, prev compute done
    asm volatile("" ::: "memory");  // fence IR motion across the barrier
    const int nkt = (kt >= 2) ? kt - 2 : 0;      // tail re-stages tile 0 (dead buf)
    STAGE(nkt, (it + 2) % 3)
    if (it) mj += d32;              // local-bias coordinate shift

    const char* KB = (const char*)Kl + buf * 4096;
    const char* VB = (const char*)Vl + buf * 4096;

    f32x4 st[2];
#pragma unroll
    for (int t = 0; t < 2; ++t) {
      st[t] = __builtin_amdgcn_mfma_f32_16x16x32_bf16(
          *(const bf16x8*)(KB + koff[t][0]), qf0, cv[t], 0, 0, 0);
      st[t] = __builtin_amdgcn_mfma_f32_16x16x32_bf16(
          *(const bf16x8*)(KB + koff[t][1]), qf1, st[t], 0, 0, 0);
    }

    const float m1 = max3f(st[0][0], st[0][1], st[0][2]);
    const float m2 = max3f(st[0][3], st[1][0], st[1][1]);
    const float m3 = max3f(st[1][2], st[1][3], m1);
    const float tm = fmaxf(m2, m3);
    if (__any(tm > mj)) {  // rare: reverse order => max found in first tiles
      float tr = fmaxf(tm, __shfl_xor(tm, 16));
      tr = fmaxf(tr, __shfl_xor(tr, 32));
      const float mn = fmaxf(mj, tr);
      const float corr = exp2_fast(mj - mn);
#pragma unroll
      for (int d = 0; d < 4; ++d) {
        oc[d][0] *= corr; oc[d][1] *= corr; oc[d][2] *= corr; oc[d][3] *= corr;
      }
      sacc[0] *= corr; sacc[1] *= corr; sacc[2] *= corr; sacc[3] *= corr;
      mj = mn;
    }

    float pe[8];
#pragma unroll
    for (int t = 0; t < 2; ++t)
#pragma unroll
      for (int i = 0; i < 4; ++i) pe[t * 4 + i] = exp2_fast(st[t][i] - mj);
    union { bf16x8 v; unsigned q[4]; } pb;
#pragma unroll
    for (int j = 0; j < 4; ++j) pb.q[j] = cvt_pk_bf16(pe[j * 2], pe[j * 2 + 1]);

#pragma unroll
    for (int db = 0; db < 4; ++db)
      oc[db] = __builtin_amdgcn_mfma_f32_16x16x32_bf16(
          *(const bf16x8*)(VB + voff[db]), pb.v, oc[db], 0, 0, 0);
    sacc = __builtin_amdgcn_mfma_f32_16x16x32_bf16(ones.v, pb.v, sacc, 0, 0, 0);
  }
#undef STAGE

  const float inv = 1.0f / sacc[0];
  u16t* orow = Ctx + base + (size_t)qpos * 1024;
#pragma unroll
  for (int d = 0; d < 4; ++d) {
    union { bf16x4 v; u16t u[4]; } o4;
#pragma unroll
    for (int i = 0; i < 4; ++i) o4.u[i] = f2bf(oc[d][i] * inv);
    *(bf16x4*)(orow + d * 16 + g * 4) = o4.v;
  }
}

extern "C" void kernel_launch(void* const* d_in, const int* in_sizes, int n_in,
                              void* d_out, int out_size, void* d_ws, size_t ws_size,
                              hipStream_t stream) {
  const float* x = (const float*)d_in[0];
  const float* Wq = (const float*)d_in[1];
  const float* bq = (const float*)d_in[2];
  const float* Wk = (const float*)d_in[3];
  const float* bk = (const float*)d_in[4];
  const float* Wv = (const float*)d_in[5];
  const float* bv = (const float*)d_in[6];
  const float* Wo = (const float*)d_in[7];
  const float* bo = (const float*)d_in[8];
  const float* slopes = (const float*)d_in[9];
  if (ws_size < (size_t)(48u << 20)) return;
  char* ws = (char*)d_ws;
  u16t* x_bf = (u16t*)(ws);                  //  8 MB: x bf16 [4096][1024]
  u16t* wqkv = (u16t*)(ws + (8u << 20));     //  6 MB: Wq|Wk|Wv bf16
  u16t* wo_bf = (u16t*)(ws + (14u << 20));   //  2 MB: Wo bf16
  u16t* q_bf = (u16t*)(ws + (16u << 20));    // 24 MB: Q | K | Vt bf16
  u16t* ctx_bf = (u16t*)(ws + (40u << 20));  //  8 MB: ctx bf16

  cvt5_kernel<<<4096, 256, 0, stream>>>(x, Wq, Wk, Wv, Wo, x_bf, wqkv, wo_bf);
  gemm_kernel<0><<<dim3(32, 24), 256, 0, stream>>>(x_bf, wqkv, bq, bk, bv, (void*)q_bf);
  attn_kernel<<<dim3(32, 32), 256, 0, stream>>>(q_bf, q_bf + 4194304, q_bf + 8388608,
                                                slopes, ctx_bf);
  gemm_kernel<1><<<dim3(32, 8), 256, 0, stream>>>(ctx_bf, wo_bf, bo, bo, bo, d_out);
}